// Round 10
// baseline (1144.387 us; speedup 1.0000x reference)
//
#include <hip/hip_runtime.h>
#include <hip/hip_bf16.h>
#include <math.h>
#include <float.h>

#define BZ 64
#define NQ 100
#define NCLS 1203
#define NO_OBJ 1202
constexpr double HUNG_INF = 1e18;
// f64_key(1e18): monotone total-order map of the reference's INF sentinel
#define KINF 0xC3ABC16D674EC800ull

// ---- cross-lane helpers (VALU/scalar, no DS ops) ----
__device__ inline double readlane_f64(double x, int l) {
  int lo = __builtin_amdgcn_readlane(__double2loint(x), l);
  int hi = __builtin_amdgcn_readlane(__double2hiint(x), l);
  return __hiloint2double(hi, lo);
}

template <int CTRL>
__device__ inline unsigned dpp_mov_u32(unsigned x) {
  return (unsigned)__builtin_amdgcn_update_dpp((int)x, (int)x, CTRL, 0xF, 0xF, false);
}
__device__ inline unsigned umin32(unsigned a, unsigned b) { return a < b ? a : b; }

// min over all 64 lanes of a u32 -> wave-uniform scalar (validated R4-R9)
__device__ inline unsigned wave_min_u32(unsigned x) {
  x = umin32(x, dpp_mov_u32<0xB1>(x));    // quad_perm xor1
  x = umin32(x, dpp_mov_u32<0x4E>(x));    // quad_perm xor2
  x = umin32(x, dpp_mov_u32<0x141>(x));   // row_half_mirror
  x = umin32(x, dpp_mov_u32<0x128>(x));   // row_ror:8 -> row16 min everywhere
  unsigned a = (unsigned)__builtin_amdgcn_readlane((int)x, 0);
  unsigned c = (unsigned)__builtin_amdgcn_readlane((int)x, 16);
  unsigned d = (unsigned)__builtin_amdgcn_readlane((int)x, 32);
  unsigned e = (unsigned)__builtin_amdgcn_readlane((int)x, 48);
  return umin32(umin32(a, c), umin32(d, e));
}

// exact min over all 64 lanes of a u64 key (used in RT/ARR, off critical tail)
__device__ inline unsigned long long wave_min_u64(unsigned long long k) {
  unsigned h = (unsigned)(k >> 32);
  unsigned KH = wave_min_u32(h);
  unsigned lo = (h == KH) ? (unsigned)k : 0xFFFFFFFFu;
  unsigned KL = wave_min_u32(lo);
  return ((unsigned long long)KH << 32) | KL;
}

// monotone bijection f64 <-> u64 (order-preserving, branchless)
__device__ inline unsigned long long f64_key(double d) {
  long long b = __double_as_longlong(d);
  long long m = (b >> 63) | (long long)0x8000000000000000ll;
  return (unsigned long long)(b ^ m);
}
__device__ inline double key_to_f64(unsigned long long k) {
  long long kk = (long long)k;
  long long m = ((~kk) >> 63) | (long long)0x8000000000000000ll;
  return __longlong_as_double(kk ^ m);
}

// ---------------- kernel A0: fused per-row stats ----------------
__global__ __launch_bounds__(64) void rowstats_kernel(
    const float* __restrict__ lab_preds,
    double* __restrict__ rowmax, double* __restrict__ rowsum,
    float* __restrict__ mxf, float* __restrict__ sf, int* __restrict__ amx) {
  const int r = blockIdx.x;
  const int t = threadIdx.x;
  const float* row = lab_preds + (size_t)r * NCLS;
  float fm = -FLT_MAX; int am = NCLS;
  for (int c = t; c < NCLS; c += 64) {
    float vv = row[c];
    if (vv > fm) { fm = vv; am = c; }
  }
#pragma unroll
  for (int off = 32; off; off >>= 1) {
    float ov = __shfl_xor(fm, off); int oi = __shfl_xor(am, off);
    if (ov > fm || (ov == fm && oi < am)) { fm = ov; am = oi; }
  }
  const double mx = (double)fm;
  double s = 0.0;
  for (int c = t; c < NCLS; c += 64) s += exp((double)row[c] - mx);
#pragma unroll
  for (int off = 32; off; off >>= 1) s += __shfl_xor(s, off);
  float sfl = 0.0f;
  for (int c = t; c < NCLS; c += 64) sfl += expf(row[c] - fm);
#pragma unroll
  for (int off = 32; off; off >>= 1) sfl += __shfl_xor(sfl, off);
  if (t == 0) {
    rowmax[r] = mx; rowsum[r] = s;
    mxf[r] = fm; sf[r] = sfl; amx[r] = am;
  }
}

// ---------------- kernel A: cost matrix + LAPJV (CR + RT + chain-ARR + Dijkstra) --------
// Column reduction, reduction transfer, faithful JV augmenting row reduction
// (immediate chain reprocessing of stolen rows on strict dual progress;
// runner-up column on ties; budget-capped with free-bit restore), then the
// R5/R7-validated register-resident Dijkstra for any leftover free rows.
// Every phase keeps duals feasible + complementary slackness; successive
// shortest path from any feasible start yields the optimal assignment, which
// is unique for continuous random costs -> gt_idx (and the loss) matches the
// numpy reference.
__global__ __launch_bounds__(64) void match_kernel(
    const int* __restrict__ labs, const float* __restrict__ lab_preds,
    const float* __restrict__ bbox, const float* __restrict__ bbox_preds,
    const double* __restrict__ rowmax, const double* __restrict__ rowsum,
    int* __restrict__ gt_idx) {
  __shared__ double2 Csh2[NQ * 64];   // 100 KB, row stride 64 double2 = 1 KB
  __shared__ int labs_sh[NQ];
  __shared__ int rowclaim[NQ];
  __shared__ double pxy[NQ][4], txy[NQ][4], pcx[NQ][4], tcx[NQ][4];
  __shared__ double areaP[NQ], areaT[NQ], rmax[NQ], rsum[NQ];

  const int b = blockIdx.x;
  const int lane = threadIdx.x;

  // stage per-batch data into LDS (doubles, mirroring the reference's f64 cast)
  for (int j = lane; j < NQ; j += 64) {
    labs_sh[j] = labs[b * NQ + j];
    const float* tb = bbox + ((size_t)b * NQ + j) * 4;
    double cx = tb[0], cy = tb[1], w = tb[2], h = tb[3];
    tcx[j][0] = cx; tcx[j][1] = cy; tcx[j][2] = w; tcx[j][3] = h;
    double x1 = cx - w * 0.5, y1 = cy - h * 0.5, x2 = cx + w * 0.5, y2 = cy + h * 0.5;
    txy[j][0] = x1; txy[j][1] = y1; txy[j][2] = x2; txy[j][3] = y2;
    areaT[j] = (x2 - x1) * (y2 - y1);
    const float* pb = bbox_preds + ((size_t)b * NQ + j) * 4;
    cx = pb[0]; cy = pb[1]; w = pb[2]; h = pb[3];
    pcx[j][0] = cx; pcx[j][1] = cy; pcx[j][2] = w; pcx[j][3] = h;
    x1 = cx - w * 0.5; y1 = cy - h * 0.5; x2 = cx + w * 0.5; y2 = cy + h * 0.5;
    pxy[j][0] = x1; pxy[j][1] = y1; pxy[j][2] = x2; pxy[j][3] = y2;
    areaP[j] = (x2 - x1) * (y2 - y1);
    rmax[j] = rowmax[b * NQ + j];
    rsum[j] = rowsum[b * NQ + j];
  }
  for (int r = lane; r < NQ; r += 64) rowclaim[r] = -1;
  __syncthreads();

  // fill cost matrix (packed layout); lane l computes cols l and l+64 of row i
  for (int i = 0; i < NQ; ++i) {
    double cA, cB = 0.0;
    {
      const int j = lane;
      double pc = exp((double)lab_preds[((size_t)b * NQ + i) * NCLS + labs_sh[j]] - rmax[i]) / rsum[i];
      double cb = fabs(pcx[i][0] - tcx[j][0]) + fabs(pcx[i][1] - tcx[j][1])
                + fabs(pcx[i][2] - tcx[j][2]) + fabs(pcx[i][3] - tcx[j][3]);
      double ltx = fmax(pxy[i][0], txy[j][0]);
      double lty = fmax(pxy[i][1], txy[j][1]);
      double rbx = fmin(pxy[i][2], txy[j][2]);
      double rby = fmin(pxy[i][3], txy[j][3]);
      double inter = fmax(rbx - ltx, 0.0) * fmax(rby - lty, 0.0);
      double uni = areaP[i] + areaT[j] - inter;
      double iou = inter / fmax(uni, 1e-9);
      cA = -pc + cb + (1.0 - iou);
    }
    if (lane + 64 < NQ) {
      const int j = lane + 64;
      double pc = exp((double)lab_preds[((size_t)b * NQ + i) * NCLS + labs_sh[j]] - rmax[i]) / rsum[i];
      double cb = fabs(pcx[i][0] - tcx[j][0]) + fabs(pcx[i][1] - tcx[j][1])
                + fabs(pcx[i][2] - tcx[j][2]) + fabs(pcx[i][3] - tcx[j][3]);
      double ltx = fmax(pxy[i][0], txy[j][0]);
      double lty = fmax(pxy[i][1], txy[j][1]);
      double rbx = fmin(pxy[i][2], txy[j][2]);
      double rby = fmin(pxy[i][3], txy[j][3]);
      double inter = fmax(rbx - ltx, 0.0) * fmax(rby - lty, 0.0);
      double uni = areaP[i] + areaT[j] - inter;
      double iou = inter / fmax(uni, 1e-9);
      cB = -pc + cb + (1.0 - iou);
    }
    Csh2[i * 64 + lane] = make_double2(cA, cB);
  }
  __syncthreads();

  const bool has1 = (lane + 65 <= NQ);   // lanes 0..35 own a second column

  // ---- Phase 1: column reduction + greedy row claim ----
  double mn0 = DBL_MAX, mn1 = DBL_MAX; int ar0 = 0, ar1 = 0;
  for (int i = 0; i < NQ; ++i) {
    double2 cd = Csh2[i * 64 + lane];
    if (cd.x < mn0) { mn0 = cd.x; ar0 = i; }
    if (has1 && cd.y < mn1) { mn1 = cd.y; ar1 = i; }
  }
  double v0 = mn0, v1 = has1 ? mn1 : 0.0;
  double u0 = 0.0, u1 = 0.0;             // u[p0c], u[p1c]
  int p0c = 0, p1c = 0;                  // matched row+1 per column (0 = free)
  if (atomicCAS(&rowclaim[ar0], -1, lane) == -1) p0c = ar0 + 1;
  if (has1 && atomicCAS(&rowclaim[ar1], -1, 64 + lane) == -1) p1c = ar1 + 1;
  __syncthreads();

  // per-row claim registers + free-row bitmasks (rows 0..63 fm0, 64..99 fm1)
  int cl0 = rowclaim[lane];                               // claim of row `lane`
  unsigned long long fm0 = __ballot(cl0 == -1);
  int cl1 = (lane < NQ - 64) ? rowclaim[64 + lane] : 0;   // claim of row 64+lane
  unsigned long long fm1 = __ballot((lane < NQ - 64) && cl1 == -1);

  // ---- Phase 1.5: reduction transfer (JV) ----
  {
    double2 cdr = Csh2[0 * 64 + lane];           // prefetch row 0
    for (int i = 0; i < NQ; ++i) {
      const int jc = (i < 64) ? __builtin_amdgcn_readlane(cl0, i)
                              : __builtin_amdgcn_readlane(cl1, i - 64);
      double2 cur = cdr;
      if (i + 1 < NQ) cdr = Csh2[(i + 1) * 64 + lane];   // prefetch next row
      if (jc < 0) continue;                       // free row: no transfer
      unsigned long long k0 = (lane == jc) ? ~0ull : f64_key(cur.x - v0);
      unsigned long long k1 = (has1 && (lane + 64) != jc) ? f64_key(cur.y - v1) : ~0ull;
      unsigned long long MU = wave_min_u64(k0 < k1 ? k0 : k1);
      double mu = key_to_f64(MU);
      if (jc < 64) { if (lane == jc) { v0 -= mu; u0 = mu; } }
      else         { if (lane == jc - 64) { v1 -= mu; u1 = mu; } }
    }
  }

  // ---- Phase 2: JV augmenting row reduction (chain version) ----
  // Strict progress (min1<min2): v[j1] -= min2-min1, assign, and IMMEDIATELY
  // reprocess the stolen row in the same chain (JV AUGROWRED). Ties: switch
  // to runner-up column; stolen row deferred. Chains end at free columns.
  // Budget-capped; an interrupted chain re-marks its row free -> Dijkstra.
  {
    int budget = 1500;
    for (int pass = 0; pass < 2 && budget > 0; ++pass) {
      unsigned long long todo0 = fm0, todo1 = fm1;
      while ((todo0 | todo1) && budget > 0) {
        int f;
        if (todo0) { f = (int)__ffsll(todo0) - 1; todo0 &= todo0 - 1; }
        else       { f = 64 + (int)__ffsll(todo1) - 1; todo1 &= todo1 - 1; }
        if (f < 64) fm0 &= ~(1ull << f); else fm1 &= ~(1ull << (f - 64));
        int i = f + 1;                     // 1-based current row of the chain
        while (true) {
          if (budget-- <= 0) {             // safety: restore freeness, bail
            int k = i - 1;
            if (k < 64) fm0 |= (1ull << k); else fm1 |= (1ull << (k - 64));
            break;
          }
          double2 cf = Csh2[(i - 1) * 64 + lane];
          unsigned long long k0 = f64_key(cf.x - v0);
          unsigned long long k1 = has1 ? f64_key(cf.y - v1) : ~0ull;
          unsigned long long K1 = wave_min_u64(k0 < k1 ? k0 : k1);
          unsigned long long bl0 = __ballot(k0 == K1);
          int lj, slot;
          if (bl0) { lj = (int)__ffsll(bl0) - 1; slot = 0; }
          else { unsigned long long bl1 = __ballot(k1 == K1); lj = (int)__ffsll(bl1) - 1; slot = 1; }
          unsigned long long k0b = (slot == 0 && lane == lj) ? ~0ull : k0;
          unsigned long long k1b = (slot == 1 && lane == lj) ? ~0ull : k1;
          unsigned long long K2 = wave_min_u64(k0b < k1b ? k0b : k1b);
          const double m2 = key_to_f64(K2);
          const bool strict = (K1 < K2);
          if (!strict) {
            // tie: if chosen column occupied, switch to the runner-up column
            int iocc = (slot == 0) ? __builtin_amdgcn_readlane(p0c, lj)
                                   : __builtin_amdgcn_readlane(p1c, lj);
            if (iocc != 0) {
              unsigned long long bl0b = __ballot(k0b == K2);
              if (bl0b) { lj = (int)__ffsll(bl0b) - 1; slot = 0; }
              else { unsigned long long bl1b = __ballot(k1b == K2); lj = (int)__ffsll(bl1b) - 1; slot = 1; }
            }
          }
          int i1 = (slot == 0) ? __builtin_amdgcn_readlane(p0c, lj)
                               : __builtin_amdgcn_readlane(p1c, lj);
          if (strict) {
            double dm = m2 - key_to_f64(K1);
            if (slot == 0 && lane == lj) v0 -= dm;
            if (slot == 1 && lane == lj) v1 -= dm;
          }
          if (slot == 0 && lane == lj) { p0c = i; u0 = m2; }
          if (slot == 1 && lane == lj) { p1c = i; u1 = m2; }
          if (i1 == 0) break;              // reached a free column: chain done
          if (strict) { i = i1; continue; }// immediate reprocess of stolen row
          { int k = i1 - 1;                // tie-steal: defer stolen row
            if (k < 64) fm0 |= (1ull << k); else fm1 |= (1ull << (k - 64)); }
          break;
        }
      }
    }
  }

  // ---- Phase 3: Dijkstra augmentation for remaining free rows (R7 loop) ----
  while (fm0 | fm1) {
    int f;
    if (fm0) { f = (int)__ffsll(fm0) - 1; fm0 &= fm0 - 1; }
    else     { f = 64 + (int)__ffsll(fm1) - 1; fm1 &= fm1 - 1; }
    const int fi = f + 1;

    double minv0 = HUNG_INF, minv1 = HUNG_INF;
    int way0 = 0, way1 = 0;
    bool used0 = false, used1 = false;
    double u_i = 0.0;                    // u[fi]=0 feasible: min(c-v) >= 0
    int j0 = 0, i0 = fi;
    double ui0 = 0.0;
    double2 cd = Csh2[(i0 - 1) * 64 + lane];   // prologue row fetch
    while (true) {
      if (j0 == lane + 1) used0 = true;
      if (j0 == lane + 65) used1 = true;

      const double c0 = cd.x;
      const double c1 = cd.y;

      if (!used0) {
        double cur = (c0 - ui0) - v0;
        if (cur < minv0) { minv0 = cur; way0 = j0; }
      }
      if (has1 && !used1) {
        double cur = (c1 - ui0) - v1;
        if (cur < minv1) { minv1 = cur; way1 = j0; }
      }
      const unsigned long long k0 = used0 ? KINF : f64_key(minv0);
      const unsigned long long k1 = has1 ? (used1 ? KINF : f64_key(minv1)) : ~0ull;

      // hi-32 reduce; exact lo-32 fallback only on (rare) hi ties
      const unsigned h0 = (unsigned)(k0 >> 32), h1 = (unsigned)(k1 >> 32);
      const unsigned KH = wave_min_u32(umin32(h0, h1));
      unsigned long long blh0 = __ballot(h0 == KH);
      unsigned long long blh1 = __ballot(h1 == KH);
      int j1, lj;
      unsigned long long KEY;
      if (__popcll(blh0) + __popcll(blh1) == 1) {
        if (blh0) {
          lj = (int)__ffsll(blh0) - 1; j1 = lj + 1;
          KEY = ((unsigned long long)KH << 32) |
                (unsigned)__builtin_amdgcn_readlane((int)(unsigned)k0, lj);
        } else {
          lj = (int)__ffsll(blh1) - 1; j1 = lj + 65;
          KEY = ((unsigned long long)KH << 32) |
                (unsigned)__builtin_amdgcn_readlane((int)(unsigned)k1, lj);
        }
      } else {
        const unsigned lo0 = (h0 == KH) ? (unsigned)k0 : 0xFFFFFFFFu;
        const unsigned lo1 = (h1 == KH) ? (unsigned)k1 : 0xFFFFFFFFu;
        const unsigned KL = wave_min_u32(umin32(lo0, lo1));
        KEY = ((unsigned long long)KH << 32) | KL;
        unsigned long long bl0 = __ballot(k0 == KEY);
        if (bl0) { lj = (int)__ffsll(bl0) - 1; j1 = lj + 1; }
        else {
          unsigned long long bl1 = __ballot(k1 == KEY);
          lj = (int)__ffsll(bl1) - 1; j1 = lj + 65;
        }
      }

      // advance pointers first so the next row fetch issues before the updates
      int pj1; double uj1;
      if (j1 <= 64) { pj1 = __builtin_amdgcn_readlane(p0c, lj); uj1 = readlane_f64(u0, lj); }
      else          { pj1 = __builtin_amdgcn_readlane(p1c, lj); uj1 = readlane_f64(u1, lj); }
      const int nrow = (pj1 > 0 ? pj1 : 1) - 1;
      double2 cd_next = Csh2[nrow * 64 + lane];   // ds_read in flight during updates

      const double delta = key_to_f64(KEY);
      // potential updates
      if (used0)        { v0 -= delta; u0 += delta; }
      else              { minv0 -= delta; }
      if (has1) {
        if (used1)      { v1 -= delta; u1 += delta; }
        else            { minv1 -= delta; }
      }
      u_i += delta;                               // j0=0 is always used

      j0 = j1; i0 = pj1; ui0 = uj1; cd = cd_next;
      if (pj1 == 0) break;
    }
    // augment along way[] chain; transfer u with p (scalar walk via readlane)
    int jj = j0;
    while (jj != 0) {
      int ljj = (jj <= 64) ? (jj - 1) : (jj - 65);
      int jn = (jj <= 64) ? __builtin_amdgcn_readlane(way0, ljj)
                          : __builtin_amdgcn_readlane(way1, ljj);
      int pn; double un;
      if (jn == 0) { pn = fi; un = u_i; }
      else {
        int ln = (jn <= 64) ? (jn - 1) : (jn - 65);
        if (jn <= 64) { pn = __builtin_amdgcn_readlane(p0c, ln); un = readlane_f64(u0, ln); }
        else          { pn = __builtin_amdgcn_readlane(p1c, ln); un = readlane_f64(u1, ln); }
      }
      if (jj == lane + 1)  { p0c = pn; u0 = un; }
      if (jj == lane + 65) { p1c = pn; u1 = un; }
      jj = jn;
    }
  }

  // col_of_row: gt_idx[p[j]-1] = j-1
  gt_idx[b * NQ + p0c - 1] = lane;
  if (has1) gt_idx[b * NQ + p1c - 1] = lane + 64;
}

// ---------------- kernel B: per-row loss from precomputed stats ----------------
__global__ __launch_bounds__(256) void lossfinal_kernel(
    const int* __restrict__ labs, const float* __restrict__ lab_preds,
    const float* __restrict__ bbox, const float* __restrict__ bbox_preds,
    const int* __restrict__ gt_idx,
    const float* __restrict__ mxf, const float* __restrict__ sf,
    const int* __restrict__ amx,
    double* __restrict__ acc, int* __restrict__ cnt_out) {
  const int r = blockIdx.x * 256 + threadIdx.x;
  double lab_t = 0.0, l1_t = 0.0, iou_t = 0.0;
  int c_t = 0;
  if (r < BZ * NQ) {
    const int b = r / NQ;
    const int g = gt_idx[r];
    const int nl = labs[b * NQ + g];
    const float val = lab_preds[(size_t)r * NCLS + nl];
    const float pg = expf(val - mxf[r]) / sf[r];
    lab_t = -(double)pg;
    if (nl != NO_OBJ && nl == amx[r]) {
      c_t = 1;
      const float* pb = bbox_preds + (size_t)r * 4;
      const float* tb = bbox + ((size_t)b * NQ + g) * 4;
      float l1 = fabsf(tb[0] - pb[0]) + fabsf(tb[1] - pb[1])
               + fabsf(tb[2] - pb[2]) + fabsf(tb[3] - pb[3]);
      l1_t = (double)l1;
      float px1 = pb[0] - pb[2] * 0.5f, py1 = pb[1] - pb[3] * 0.5f;
      float px2 = pb[0] + pb[2] * 0.5f, py2 = pb[1] + pb[3] * 0.5f;
      float tx1 = tb[0] - tb[2] * 0.5f, ty1 = tb[1] - tb[3] * 0.5f;
      float tx2 = tb[0] + tb[2] * 0.5f, ty2 = tb[1] + tb[3] * 0.5f;
      float ltx = fmaxf(px1, tx1), lty = fmaxf(py1, ty1);
      float rbx = fminf(px2, tx2), rby = fminf(py2, ty2);
      float inter = fmaxf(rbx - ltx, 0.0f) * fmaxf(rby - lty, 0.0f);
      float uni = (px2 - px1) * (py2 - py1) + (tx2 - tx1) * (ty2 - ty1) - inter;
      float iou = inter / fmaxf(uni, 1e-9f);
      iou_t = (double)(1.0f - iou);
    }
  }
#pragma unroll
  for (int off = 32; off; off >>= 1) {
    lab_t += __shfl_xor(lab_t, off);
    l1_t  += __shfl_xor(l1_t, off);
    iou_t += __shfl_xor(iou_t, off);
    c_t   += __shfl_xor(c_t, off);
  }
  __shared__ double s_lab[4], s_l1[4], s_iou[4];
  __shared__ int s_cnt[4];
  const int wave = threadIdx.x >> 6;
  if ((threadIdx.x & 63) == 0) { s_lab[wave] = lab_t; s_l1[wave] = l1_t; s_iou[wave] = iou_t; s_cnt[wave] = c_t; }
  __syncthreads();
  if (threadIdx.x == 0) {
    double a = 0.0, bb = 0.0, c = 0.0; int n = 0;
    for (int w = 0; w < 4; ++w) { a += s_lab[w]; bb += s_l1[w]; c += s_iou[w]; n += s_cnt[w]; }
    atomicAdd(&acc[0], a);
    atomicAdd(&acc[1], bb);
    atomicAdd(&acc[2], c);
    atomicAdd(cnt_out, n);
  }
}

// ---------------- kernel C: combine ----------------
__global__ void finalize_kernel(const double* __restrict__ acc, const int* __restrict__ cnt,
                                float* __restrict__ out) {
  int n = *cnt; if (n < 1) n = 1;
  out[0] = (float)(acc[0] / (double)(BZ * NQ) + acc[1] + acc[2] / (double)n);
}

extern "C" void kernel_launch(void* const* d_in, const int* in_sizes, int n_in,
                              void* d_out, int out_size, void* d_ws, size_t ws_size,
                              hipStream_t stream) {
  const int*   labs       = (const int*)d_in[0];
  const float* lab_preds  = (const float*)d_in[1];
  const float* bbox       = (const float*)d_in[2];
  const float* bbox_preds = (const float*)d_in[3];

  char* ws = (char*)d_ws;
  int*    gt_idx = (int*)ws;                         // 25600 B
  double* acc    = (double*)(ws + 25600);            // 3 doubles
  int*    cnt    = (int*)(ws + 25624);               // 1 int (+4 pad)
  double* rowmax = (double*)(ws + 25632);            // 51200 B
  double* rowsum = (double*)(ws + 76832);            // 51200 B
  float*  mxf    = (float*)(ws + 128032);            // 25600 B
  float*  sfw    = (float*)(ws + 153632);            // 25600 B
  int*    amx    = (int*)(ws + 179232);              // 25600 B

  hipMemsetAsync(ws + 25600, 0, 32, stream);         // zero accumulators
  rowstats_kernel<<<BZ * NQ, 64, 0, stream>>>(lab_preds, rowmax, rowsum, mxf, sfw, amx);
  match_kernel<<<BZ, 64, 0, stream>>>(labs, lab_preds, bbox, bbox_preds, rowmax, rowsum, gt_idx);
  lossfinal_kernel<<<(BZ * NQ + 255) / 256, 256, 0, stream>>>(
      labs, lab_preds, bbox, bbox_preds, gt_idx, mxf, sfw, amx, acc, cnt);
  finalize_kernel<<<1, 1, 0, stream>>>(acc, cnt, (float*)d_out);
}

// Round 11
// 447.464 us; speedup vs baseline: 2.5575x; 2.5575x over previous
//
#include <hip/hip_runtime.h>
#include <hip/hip_bf16.h>
#include <math.h>
#include <float.h>

#define BZ 64
#define NQ 100
#define NCLS 1203
#define NO_OBJ 1202
constexpr double HUNG_INF = 1e18;
// f64_key(1e18): monotone total-order map of the reference's INF sentinel
#define KINF 0xC3ABC16D674EC800ull

// ---- cross-lane helpers (VALU/scalar, no DS ops) ----
__device__ inline double readlane_f64(double x, int l) {
  int lo = __builtin_amdgcn_readlane(__double2loint(x), l);
  int hi = __builtin_amdgcn_readlane(__double2hiint(x), l);
  return __hiloint2double(hi, lo);
}

template <int CTRL>
__device__ inline unsigned dpp_mov_u32(unsigned x) {
  return (unsigned)__builtin_amdgcn_update_dpp((int)x, (int)x, CTRL, 0xF, 0xF, false);
}
__device__ inline unsigned umin32(unsigned a, unsigned b) { return a < b ? a : b; }

// min over all 64 lanes of a u32 -> wave-uniform scalar (validated R4-R9)
__device__ inline unsigned wave_min_u32(unsigned x) {
  x = umin32(x, dpp_mov_u32<0xB1>(x));    // quad_perm xor1
  x = umin32(x, dpp_mov_u32<0x4E>(x));    // quad_perm xor2
  x = umin32(x, dpp_mov_u32<0x141>(x));   // row_half_mirror
  x = umin32(x, dpp_mov_u32<0x128>(x));   // row_ror:8 -> row16 min everywhere
  unsigned a = (unsigned)__builtin_amdgcn_readlane((int)x, 0);
  unsigned c = (unsigned)__builtin_amdgcn_readlane((int)x, 16);
  unsigned d = (unsigned)__builtin_amdgcn_readlane((int)x, 32);
  unsigned e = (unsigned)__builtin_amdgcn_readlane((int)x, 48);
  return umin32(umin32(a, c), umin32(d, e));
}

// exact min over all 64 lanes of a u64 key (used in RT/ARR, off critical tail)
__device__ inline unsigned long long wave_min_u64(unsigned long long k) {
  unsigned h = (unsigned)(k >> 32);
  unsigned KH = wave_min_u32(h);
  unsigned lo = (h == KH) ? (unsigned)k : 0xFFFFFFFFu;
  unsigned KL = wave_min_u32(lo);
  return ((unsigned long long)KH << 32) | KL;
}

// monotone bijection f64 <-> u64 (order-preserving, branchless)
__device__ inline unsigned long long f64_key(double d) {
  long long b = __double_as_longlong(d);
  long long m = (b >> 63) | (long long)0x8000000000000000ll;
  return (unsigned long long)(b ^ m);
}
__device__ inline double key_to_f64(unsigned long long k) {
  long long kk = (long long)k;
  long long m = ((~kk) >> 63) | (long long)0x8000000000000000ll;
  return __longlong_as_double(kk ^ m);
}

// ---------------- kernel A0: fused per-row stats ----------------
__global__ __launch_bounds__(64) void rowstats_kernel(
    const float* __restrict__ lab_preds,
    double* __restrict__ rowmax, double* __restrict__ rowsum,
    float* __restrict__ mxf, float* __restrict__ sf, int* __restrict__ amx) {
  const int r = blockIdx.x;
  const int t = threadIdx.x;
  const float* row = lab_preds + (size_t)r * NCLS;
  float fm = -FLT_MAX; int am = NCLS;
  for (int c = t; c < NCLS; c += 64) {
    float vv = row[c];
    if (vv > fm) { fm = vv; am = c; }
  }
#pragma unroll
  for (int off = 32; off; off >>= 1) {
    float ov = __shfl_xor(fm, off); int oi = __shfl_xor(am, off);
    if (ov > fm || (ov == fm && oi < am)) { fm = ov; am = oi; }
  }
  const double mx = (double)fm;
  double s = 0.0;
  for (int c = t; c < NCLS; c += 64) s += exp((double)row[c] - mx);
#pragma unroll
  for (int off = 32; off; off >>= 1) s += __shfl_xor(s, off);
  float sfl = 0.0f;
  for (int c = t; c < NCLS; c += 64) sfl += expf(row[c] - fm);
#pragma unroll
  for (int off = 32; off; off >>= 1) sfl += __shfl_xor(sfl, off);
  if (t == 0) {
    rowmax[r] = mx; rowsum[r] = s;
    mxf[r] = fm; sf[r] = sfl; amx[r] = am;
  }
}

// ---------------- kernel A: cost matrix + LAPJV (CR + RT + ARR + Dijkstra) ----------------
// Column reduction, reduction transfer (JV), 2-pass deferred augmenting row
// reduction (bounded by construction), then the R5/R7-validated register-
// resident Dijkstra for the remaining free rows. Every phase keeps duals
// feasible + complementary slackness; successive shortest path from any
// feasible start yields the optimal assignment, which is unique for
// continuous random costs -> gt_idx (and the loss) matches the numpy
// reference. (Chain-ARR rejected in R10: near-tied costs make steal chains
// random-walk; this deferred form is the measured optimum.)
__global__ __launch_bounds__(64) void match_kernel(
    const int* __restrict__ labs, const float* __restrict__ lab_preds,
    const float* __restrict__ bbox, const float* __restrict__ bbox_preds,
    const double* __restrict__ rowmax, const double* __restrict__ rowsum,
    int* __restrict__ gt_idx) {
  __shared__ double2 Csh2[NQ * 64];   // 100 KB, row stride 64 double2 = 1 KB
  __shared__ int labs_sh[NQ];
  __shared__ int rowclaim[NQ];
  __shared__ double pxy[NQ][4], txy[NQ][4], pcx[NQ][4], tcx[NQ][4];
  __shared__ double areaP[NQ], areaT[NQ], rmax[NQ], rsum[NQ];

  const int b = blockIdx.x;
  const int lane = threadIdx.x;

  // stage per-batch data into LDS (doubles, mirroring the reference's f64 cast)
  for (int j = lane; j < NQ; j += 64) {
    labs_sh[j] = labs[b * NQ + j];
    const float* tb = bbox + ((size_t)b * NQ + j) * 4;
    double cx = tb[0], cy = tb[1], w = tb[2], h = tb[3];
    tcx[j][0] = cx; tcx[j][1] = cy; tcx[j][2] = w; tcx[j][3] = h;
    double x1 = cx - w * 0.5, y1 = cy - h * 0.5, x2 = cx + w * 0.5, y2 = cy + h * 0.5;
    txy[j][0] = x1; txy[j][1] = y1; txy[j][2] = x2; txy[j][3] = y2;
    areaT[j] = (x2 - x1) * (y2 - y1);
    const float* pb = bbox_preds + ((size_t)b * NQ + j) * 4;
    cx = pb[0]; cy = pb[1]; w = pb[2]; h = pb[3];
    pcx[j][0] = cx; pcx[j][1] = cy; pcx[j][2] = w; pcx[j][3] = h;
    x1 = cx - w * 0.5; y1 = cy - h * 0.5; x2 = cx + w * 0.5; y2 = cy + h * 0.5;
    pxy[j][0] = x1; pxy[j][1] = y1; pxy[j][2] = x2; pxy[j][3] = y2;
    areaP[j] = (x2 - x1) * (y2 - y1);
    rmax[j] = rowmax[b * NQ + j];
    rsum[j] = rowsum[b * NQ + j];
  }
  for (int r = lane; r < NQ; r += 64) rowclaim[r] = -1;
  __syncthreads();

  // fill cost matrix (packed layout); lane l computes cols l and l+64 of row i
  for (int i = 0; i < NQ; ++i) {
    double cA, cB = 0.0;
    {
      const int j = lane;
      double pc = exp((double)lab_preds[((size_t)b * NQ + i) * NCLS + labs_sh[j]] - rmax[i]) / rsum[i];
      double cb = fabs(pcx[i][0] - tcx[j][0]) + fabs(pcx[i][1] - tcx[j][1])
                + fabs(pcx[i][2] - tcx[j][2]) + fabs(pcx[i][3] - tcx[j][3]);
      double ltx = fmax(pxy[i][0], txy[j][0]);
      double lty = fmax(pxy[i][1], txy[j][1]);
      double rbx = fmin(pxy[i][2], txy[j][2]);
      double rby = fmin(pxy[i][3], txy[j][3]);
      double inter = fmax(rbx - ltx, 0.0) * fmax(rby - lty, 0.0);
      double uni = areaP[i] + areaT[j] - inter;
      double iou = inter / fmax(uni, 1e-9);
      cA = -pc + cb + (1.0 - iou);
    }
    if (lane + 64 < NQ) {
      const int j = lane + 64;
      double pc = exp((double)lab_preds[((size_t)b * NQ + i) * NCLS + labs_sh[j]] - rmax[i]) / rsum[i];
      double cb = fabs(pcx[i][0] - tcx[j][0]) + fabs(pcx[i][1] - tcx[j][1])
                + fabs(pcx[i][2] - tcx[j][2]) + fabs(pcx[i][3] - tcx[j][3]);
      double ltx = fmax(pxy[i][0], txy[j][0]);
      double lty = fmax(pxy[i][1], txy[j][1]);
      double rbx = fmin(pxy[i][2], txy[j][2]);
      double rby = fmin(pxy[i][3], txy[j][3]);
      double inter = fmax(rbx - ltx, 0.0) * fmax(rby - lty, 0.0);
      double uni = areaP[i] + areaT[j] - inter;
      double iou = inter / fmax(uni, 1e-9);
      cB = -pc + cb + (1.0 - iou);
    }
    Csh2[i * 64 + lane] = make_double2(cA, cB);
  }
  __syncthreads();

  const bool has1 = (lane + 65 <= NQ);   // lanes 0..35 own a second column

  // ---- Phase 1: column reduction + greedy row claim ----
  double mn0 = DBL_MAX, mn1 = DBL_MAX; int ar0 = 0, ar1 = 0;
  for (int i = 0; i < NQ; ++i) {
    double2 cd = Csh2[i * 64 + lane];
    if (cd.x < mn0) { mn0 = cd.x; ar0 = i; }
    if (has1 && cd.y < mn1) { mn1 = cd.y; ar1 = i; }
  }
  double v0 = mn0, v1 = has1 ? mn1 : 0.0;
  double u0 = 0.0, u1 = 0.0;             // u[p0c], u[p1c]
  int p0c = 0, p1c = 0;                  // matched row+1 per column (0 = free)
  if (atomicCAS(&rowclaim[ar0], -1, lane) == -1) p0c = ar0 + 1;
  if (has1 && atomicCAS(&rowclaim[ar1], -1, 64 + lane) == -1) p1c = ar1 + 1;
  __syncthreads();

  // per-row claim registers + free-row bitmasks (rows 0..63 fm0, 64..99 fm1)
  int cl0 = rowclaim[lane];                               // claim of row `lane`
  unsigned long long fm0 = __ballot(cl0 == -1);
  int cl1 = (lane < NQ - 64) ? rowclaim[64 + lane] : 0;   // claim of row 64+lane
  unsigned long long fm1 = __ballot((lane < NQ - 64) && cl1 == -1);

  // ---- Phase 1.5: reduction transfer (JV) ----
  // For each CR-assigned row i (claimed column jc): mu = min_{j!=jc}(c[i][j]-v[j]);
  // v[jc] -= mu; u[i] = mu. Duals stay feasible, CS holds (c[i][jc]=v_old[jc]).
  {
    double2 cdr = Csh2[0 * 64 + lane];           // prefetch row 0
    for (int i = 0; i < NQ; ++i) {
      const int jc = (i < 64) ? __builtin_amdgcn_readlane(cl0, i)
                              : __builtin_amdgcn_readlane(cl1, i - 64);
      double2 cur = cdr;
      if (i + 1 < NQ) cdr = Csh2[(i + 1) * 64 + lane];   // prefetch next row
      if (jc < 0) continue;                       // free row: no transfer
      unsigned long long k0 = (lane == jc) ? ~0ull : f64_key(cur.x - v0);
      unsigned long long k1 = (has1 && (lane + 64) != jc) ? f64_key(cur.y - v1) : ~0ull;
      unsigned long long MU = wave_min_u64(k0 < k1 ? k0 : k1);
      double mu = key_to_f64(MU);
      if (jc < 64) { if (lane == jc) { v0 -= mu; u0 = mu; } }
      else         { if (lane == jc - 64) { v1 -= mu; u1 = mu; } }
    }
  }

  // ---- Phase 2: LAPJV augmenting row reduction, 2 passes (deferred steals) ----
  // Strict dual progress on min1<min2; runner-up column on tie-with-occupied;
  // snapshot todo lists -> each pass processes each listed row once (bounded).
  for (int pass = 0; pass < 2; ++pass) {
    unsigned long long todo0 = fm0, todo1 = fm1;
    while (todo0 | todo1) {
      int f;
      if (todo0) { f = (int)__ffsll(todo0) - 1; todo0 &= todo0 - 1; }
      else       { f = 64 + (int)__ffsll(todo1) - 1; todo1 &= todo1 - 1; }
      double2 cf = Csh2[f * 64 + lane];
      unsigned long long k0 = f64_key(cf.x - v0);
      unsigned long long k1 = has1 ? f64_key(cf.y - v1) : ~0ull;
      unsigned long long K1 = wave_min_u64(k0 < k1 ? k0 : k1);
      unsigned long long bl0 = __ballot(k0 == K1);
      int lj, slot;
      if (bl0) { lj = (int)__ffsll(bl0) - 1; slot = 0; }
      else { unsigned long long bl1 = __ballot(k1 == K1); lj = (int)__ffsll(bl1) - 1; slot = 1; }
      unsigned long long k0b = (slot == 0 && lane == lj) ? ~0ull : k0;
      unsigned long long k1b = (slot == 1 && lane == lj) ? ~0ull : k1;
      unsigned long long K2 = wave_min_u64(k0b < k1b ? k0b : k1b);
      const double m2 = key_to_f64(K2);
      int i1 = (slot == 0) ? __builtin_amdgcn_readlane(p0c, lj)
                           : __builtin_amdgcn_readlane(p1c, lj);
      if (K1 < K2) {
        // strict: dual progress at j1
        double dm = m2 - key_to_f64(K1);
        if (slot == 0 && lane == lj) v0 -= dm;
        if (slot == 1 && lane == lj) v1 -= dm;
      } else if (i1 != 0) {
        // tie with occupied column: switch to the runner-up column
        unsigned long long bl0b = __ballot(k0b == K2);
        if (bl0b) { lj = (int)__ffsll(bl0b) - 1; slot = 0; }
        else { unsigned long long bl1b = __ballot(k1b == K2); lj = (int)__ffsll(bl1b) - 1; slot = 1; }
        i1 = (slot == 0) ? __builtin_amdgcn_readlane(p0c, lj)
                         : __builtin_amdgcn_readlane(p1c, lj);
      }
      // assign f to chosen column; its u = min2 (feasible, CS holds)
      if (slot == 0 && lane == lj) { p0c = f + 1; u0 = m2; }
      if (slot == 1 && lane == lj) { p1c = f + 1; u1 = m2; }
      if (f < 64) fm0 &= ~(1ull << f); else fm1 &= ~(1ull << (f - 64));
      if (i1 != 0) {   // freed row -> live mask (next pass or Dijkstra)
        int k = i1 - 1;
        if (k < 64) fm0 |= (1ull << k); else fm1 |= (1ull << (k - 64));
      }
    }
  }

  // ---- Phase 3: Dijkstra augmentation for remaining free rows (R7 loop) ----
  while (fm0 | fm1) {
    int f;
    if (fm0) { f = (int)__ffsll(fm0) - 1; fm0 &= fm0 - 1; }
    else     { f = 64 + (int)__ffsll(fm1) - 1; fm1 &= fm1 - 1; }
    const int fi = f + 1;

    double minv0 = HUNG_INF, minv1 = HUNG_INF;
    int way0 = 0, way1 = 0;
    bool used0 = false, used1 = false;
    double u_i = 0.0;                    // u[fi]=0 feasible: min(c-v) >= 0
    int j0 = 0, i0 = fi;
    double ui0 = 0.0;
    double2 cd = Csh2[(i0 - 1) * 64 + lane];   // prologue row fetch
    while (true) {
      if (j0 == lane + 1) used0 = true;
      if (j0 == lane + 65) used1 = true;

      const double c0 = cd.x;
      const double c1 = cd.y;

      if (!used0) {
        double cur = (c0 - ui0) - v0;
        if (cur < minv0) { minv0 = cur; way0 = j0; }
      }
      if (has1 && !used1) {
        double cur = (c1 - ui0) - v1;
        if (cur < minv1) { minv1 = cur; way1 = j0; }
      }
      const unsigned long long k0 = used0 ? KINF : f64_key(minv0);
      const unsigned long long k1 = has1 ? (used1 ? KINF : f64_key(minv1)) : ~0ull;

      // hi-32 reduce; exact lo-32 fallback only on (rare) hi ties
      const unsigned h0 = (unsigned)(k0 >> 32), h1 = (unsigned)(k1 >> 32);
      const unsigned KH = wave_min_u32(umin32(h0, h1));
      unsigned long long blh0 = __ballot(h0 == KH);
      unsigned long long blh1 = __ballot(h1 == KH);
      int j1, lj;
      unsigned long long KEY;
      if (__popcll(blh0) + __popcll(blh1) == 1) {
        if (blh0) {
          lj = (int)__ffsll(blh0) - 1; j1 = lj + 1;
          KEY = ((unsigned long long)KH << 32) |
                (unsigned)__builtin_amdgcn_readlane((int)(unsigned)k0, lj);
        } else {
          lj = (int)__ffsll(blh1) - 1; j1 = lj + 65;
          KEY = ((unsigned long long)KH << 32) |
                (unsigned)__builtin_amdgcn_readlane((int)(unsigned)k1, lj);
        }
      } else {
        const unsigned lo0 = (h0 == KH) ? (unsigned)k0 : 0xFFFFFFFFu;
        const unsigned lo1 = (h1 == KH) ? (unsigned)k1 : 0xFFFFFFFFu;
        const unsigned KL = wave_min_u32(umin32(lo0, lo1));
        KEY = ((unsigned long long)KH << 32) | KL;
        unsigned long long bl0 = __ballot(k0 == KEY);
        if (bl0) { lj = (int)__ffsll(bl0) - 1; j1 = lj + 1; }
        else {
          unsigned long long bl1 = __ballot(k1 == KEY);
          lj = (int)__ffsll(bl1) - 1; j1 = lj + 65;
        }
      }

      // advance pointers first so the next row fetch issues before the updates
      int pj1; double uj1;
      if (j1 <= 64) { pj1 = __builtin_amdgcn_readlane(p0c, lj); uj1 = readlane_f64(u0, lj); }
      else          { pj1 = __builtin_amdgcn_readlane(p1c, lj); uj1 = readlane_f64(u1, lj); }
      const int nrow = (pj1 > 0 ? pj1 : 1) - 1;
      double2 cd_next = Csh2[nrow * 64 + lane];   // ds_read in flight during updates

      const double delta = key_to_f64(KEY);
      // potential updates
      if (used0)        { v0 -= delta; u0 += delta; }
      else              { minv0 -= delta; }
      if (has1) {
        if (used1)      { v1 -= delta; u1 += delta; }
        else            { minv1 -= delta; }
      }
      u_i += delta;                               // j0=0 is always used

      j0 = j1; i0 = pj1; ui0 = uj1; cd = cd_next;
      if (pj1 == 0) break;
    }
    // augment along way[] chain; transfer u with p (scalar walk via readlane)
    int jj = j0;
    while (jj != 0) {
      int ljj = (jj <= 64) ? (jj - 1) : (jj - 65);
      int jn = (jj <= 64) ? __builtin_amdgcn_readlane(way0, ljj)
                          : __builtin_amdgcn_readlane(way1, ljj);
      int pn; double un;
      if (jn == 0) { pn = fi; un = u_i; }
      else {
        int ln = (jn <= 64) ? (jn - 1) : (jn - 65);
        if (jn <= 64) { pn = __builtin_amdgcn_readlane(p0c, ln); un = readlane_f64(u0, ln); }
        else          { pn = __builtin_amdgcn_readlane(p1c, ln); un = readlane_f64(u1, ln); }
      }
      if (jj == lane + 1)  { p0c = pn; u0 = un; }
      if (jj == lane + 65) { p1c = pn; u1 = un; }
      jj = jn;
    }
  }

  // col_of_row: gt_idx[p[j]-1] = j-1
  gt_idx[b * NQ + p0c - 1] = lane;
  if (has1) gt_idx[b * NQ + p1c - 1] = lane + 64;
}

// ---------------- kernel B: per-row loss from precomputed stats ----------------
__global__ __launch_bounds__(256) void lossfinal_kernel(
    const int* __restrict__ labs, const float* __restrict__ lab_preds,
    const float* __restrict__ bbox, const float* __restrict__ bbox_preds,
    const int* __restrict__ gt_idx,
    const float* __restrict__ mxf, const float* __restrict__ sf,
    const int* __restrict__ amx,
    double* __restrict__ acc, int* __restrict__ cnt_out) {
  const int r = blockIdx.x * 256 + threadIdx.x;
  double lab_t = 0.0, l1_t = 0.0, iou_t = 0.0;
  int c_t = 0;
  if (r < BZ * NQ) {
    const int b = r / NQ;
    const int g = gt_idx[r];
    const int nl = labs[b * NQ + g];
    const float val = lab_preds[(size_t)r * NCLS + nl];
    const float pg = expf(val - mxf[r]) / sf[r];
    lab_t = -(double)pg;
    if (nl != NO_OBJ && nl == amx[r]) {
      c_t = 1;
      const float* pb = bbox_preds + (size_t)r * 4;
      const float* tb = bbox + ((size_t)b * NQ + g) * 4;
      float l1 = fabsf(tb[0] - pb[0]) + fabsf(tb[1] - pb[1])
               + fabsf(tb[2] - pb[2]) + fabsf(tb[3] - pb[3]);
      l1_t = (double)l1;
      float px1 = pb[0] - pb[2] * 0.5f, py1 = pb[1] - pb[3] * 0.5f;
      float px2 = pb[0] + pb[2] * 0.5f, py2 = pb[1] + pb[3] * 0.5f;
      float tx1 = tb[0] - tb[2] * 0.5f, ty1 = tb[1] - tb[3] * 0.5f;
      float tx2 = tb[0] + tb[2] * 0.5f, ty2 = tb[1] + tb[3] * 0.5f;
      float ltx = fmaxf(px1, tx1), lty = fmaxf(py1, ty1);
      float rbx = fminf(px2, tx2), rby = fminf(py2, ty2);
      float inter = fmaxf(rbx - ltx, 0.0f) * fmaxf(rby - lty, 0.0f);
      float uni = (px2 - px1) * (py2 - py1) + (tx2 - tx1) * (ty2 - ty1) - inter;
      float iou = inter / fmaxf(uni, 1e-9f);
      iou_t = (double)(1.0f - iou);
    }
  }
#pragma unroll
  for (int off = 32; off; off >>= 1) {
    lab_t += __shfl_xor(lab_t, off);
    l1_t  += __shfl_xor(l1_t, off);
    iou_t += __shfl_xor(iou_t, off);
    c_t   += __shfl_xor(c_t, off);
  }
  __shared__ double s_lab[4], s_l1[4], s_iou[4];
  __shared__ int s_cnt[4];
  const int wave = threadIdx.x >> 6;
  if ((threadIdx.x & 63) == 0) { s_lab[wave] = lab_t; s_l1[wave] = l1_t; s_iou[wave] = iou_t; s_cnt[wave] = c_t; }
  __syncthreads();
  if (threadIdx.x == 0) {
    double a = 0.0, bb = 0.0, c = 0.0; int n = 0;
    for (int w = 0; w < 4; ++w) { a += s_lab[w]; bb += s_l1[w]; c += s_iou[w]; n += s_cnt[w]; }
    atomicAdd(&acc[0], a);
    atomicAdd(&acc[1], bb);
    atomicAdd(&acc[2], c);
    atomicAdd(cnt_out, n);
  }
}

// ---------------- kernel C: combine ----------------
__global__ void finalize_kernel(const double* __restrict__ acc, const int* __restrict__ cnt,
                                float* __restrict__ out) {
  int n = *cnt; if (n < 1) n = 1;
  out[0] = (float)(acc[0] / (double)(BZ * NQ) + acc[1] + acc[2] / (double)n);
}

extern "C" void kernel_launch(void* const* d_in, const int* in_sizes, int n_in,
                              void* d_out, int out_size, void* d_ws, size_t ws_size,
                              hipStream_t stream) {
  const int*   labs       = (const int*)d_in[0];
  const float* lab_preds  = (const float*)d_in[1];
  const float* bbox       = (const float*)d_in[2];
  const float* bbox_preds = (const float*)d_in[3];

  char* ws = (char*)d_ws;
  int*    gt_idx = (int*)ws;                         // 25600 B
  double* acc    = (double*)(ws + 25600);            // 3 doubles
  int*    cnt    = (int*)(ws + 25624);               // 1 int (+4 pad)
  double* rowmax = (double*)(ws + 25632);            // 51200 B
  double* rowsum = (double*)(ws + 76832);            // 51200 B
  float*  mxf    = (float*)(ws + 128032);            // 25600 B
  float*  sfw    = (float*)(ws + 153632);            // 25600 B
  int*    amx    = (int*)(ws + 179232);              // 25600 B

  hipMemsetAsync(ws + 25600, 0, 32, stream);         // zero accumulators
  rowstats_kernel<<<BZ * NQ, 64, 0, stream>>>(lab_preds, rowmax, rowsum, mxf, sfw, amx);
  match_kernel<<<BZ, 64, 0, stream>>>(labs, lab_preds, bbox, bbox_preds, rowmax, rowsum, gt_idx);
  lossfinal_kernel<<<(BZ * NQ + 255) / 256, 256, 0, stream>>>(
      labs, lab_preds, bbox, bbox_preds, gt_idx, mxf, sfw, amx, acc, cnt);
  finalize_kernel<<<1, 1, 0, stream>>>(acc, cnt, (float*)d_out);
}